// Round 1
// baseline (244.425 us; speedup 1.0000x reference)
//
#include <hip/hip_runtime.h>
#include <math.h>

#define TT 100
#define NN 100
#define DD 1024
#define HH 8192
#define ILR 0.01f

__device__ __forceinline__ float wave_sum64(float v) {
#pragma unroll
  for (int off = 32; off; off >>= 1) v += __shfl_xor(v, off, 64);
  return v;
}

// ---------------- K1: Hall[r][j] = tanh(sum_k Xall[r][k]*W[k][j] + b[j]), r<200
__global__ __launch_bounds__(256) void k1_hidden(const float* __restrict__ xt,
                                                 const float* __restrict__ xr,
                                                 const float* __restrict__ W,
                                                 const float* __restrict__ bias,
                                                 float* __restrict__ Hall) {
  __shared__ float As[16 * 68];  // [k][row], stride 68 (pad for xpose-write conflicts, 16B-aligned)
  __shared__ float Bs[16 * 64];  // [k][col]
  const int tid = threadIdx.x;
  const int row0 = blockIdx.x * 64;
  const int col0 = blockIdx.y * 64;
  const int tx = tid & 15, ty = tid >> 4;
  const int lr_ = tid >> 2;  // 0..63 A-load row
  const int lkq = tid & 3;   // 0..3
  const int lbk = tid >> 4;  // 0..15 B-load k
  const int lbj = (tid & 15) * 4;

  float acc[4][4];
#pragma unroll
  for (int i = 0; i < 4; i++)
#pragma unroll
    for (int j = 0; j < 4; j++) acc[i][j] = 0.f;

  for (int k0 = 0; k0 < DD; k0 += 16) {
    float4 av;
    const int grow = row0 + lr_;
    if (grow < 200) {
      const float* src = (grow < TT) ? (xt + grow * DD) : (xr + (grow - TT) * DD);
      av = *(const float4*)(src + k0 + lkq * 4);
    } else {
      av = make_float4(0.f, 0.f, 0.f, 0.f);
    }
    const float4 bv = *(const float4*)(W + (k0 + lbk) * HH + col0 + lbj);
    __syncthreads();
    As[(lkq * 4 + 0) * 68 + lr_] = av.x;
    As[(lkq * 4 + 1) * 68 + lr_] = av.y;
    As[(lkq * 4 + 2) * 68 + lr_] = av.z;
    As[(lkq * 4 + 3) * 68 + lr_] = av.w;
    *(float4*)&Bs[lbk * 64 + lbj] = bv;
    __syncthreads();
#pragma unroll
    for (int k = 0; k < 16; k++) {
      const float4 a4 = *(const float4*)&As[k * 68 + ty * 4];
      const float4 b4 = *(const float4*)&Bs[k * 64 + tx * 4];
      const float a_[4] = {a4.x, a4.y, a4.z, a4.w};
      const float b_[4] = {b4.x, b4.y, b4.z, b4.w};
#pragma unroll
      for (int i = 0; i < 4; i++)
#pragma unroll
        for (int j = 0; j < 4; j++) acc[i][j] = fmaf(a_[i], b_[j], acc[i][j]);
    }
  }
  const float4 bb = *(const float4*)(bias + col0 + tx * 4);
  const float bbv[4] = {bb.x, bb.y, bb.z, bb.w};
#pragma unroll
  for (int i = 0; i < 4; i++) {
    const int r = row0 + ty * 4 + i;
    if (r < 200) {
      float4 hv;
      hv.x = tanhf(acc[i][0] + bbv[0]);
      hv.y = tanhf(acc[i][1] + bbv[1]);
      hv.z = tanhf(acc[i][2] + bbv[2]);
      hv.w = tanhf(acc[i][3] + bbv[3]);
      *(float4*)(Hall + r * HH + col0 + tx * 4) = hv;
    }
  }
}

// ---------------- K2: Gram G[s][t] = Ht[s]·Ht[t] (2x2 tiles per wave) + y0[t] = Ht[t]·w0
__global__ __launch_bounds__(256) void k2_gram(const float* __restrict__ Ht,
                                               const float* __restrict__ w0,
                                               float* __restrict__ G,
                                               float* __restrict__ y0) {
  const int wid = blockIdx.x * 4 + (threadIdx.x >> 6);
  const int lane = threadIdx.x & 63;
  if (wid < 1275) {
    int a = 0, rem = wid;
    while (rem >= 50 - a) { rem -= 50 - a; a++; }
    const int bt = a + rem;
    const int s0 = a * 2, t0 = bt * 2;
    const float* r0 = Ht + s0 * HH;
    const float* r1 = Ht + (s0 + 1) * HH;
    const float* c0 = Ht + t0 * HH;
    const float* c1 = Ht + (t0 + 1) * HH;
    float a00 = 0.f, a01 = 0.f, a10 = 0.f, a11 = 0.f;
#pragma unroll 4
    for (int i = 0; i < 32; i++) {
      const int k = (lane + i * 64) * 4;
      const float4 x0 = *(const float4*)(r0 + k);
      const float4 x1 = *(const float4*)(r1 + k);
      const float4 u0 = *(const float4*)(c0 + k);
      const float4 u1 = *(const float4*)(c1 + k);
      a00 += x0.x * u0.x + x0.y * u0.y + x0.z * u0.z + x0.w * u0.w;
      a01 += x0.x * u1.x + x0.y * u1.y + x0.z * u1.z + x0.w * u1.w;
      a10 += x1.x * u0.x + x1.y * u0.y + x1.z * u0.z + x1.w * u0.w;
      a11 += x1.x * u1.x + x1.y * u1.y + x1.z * u1.z + x1.w * u1.w;
    }
    a00 = wave_sum64(a00);
    a01 = wave_sum64(a01);
    a10 = wave_sum64(a10);
    a11 = wave_sum64(a11);
    if (lane == 0) {
      G[s0 * 100 + t0] = a00;             G[t0 * 100 + s0] = a00;
      G[s0 * 100 + t0 + 1] = a01;         G[(t0 + 1) * 100 + s0] = a01;
      G[(s0 + 1) * 100 + t0] = a10;       G[t0 * 100 + s0 + 1] = a10;
      G[(s0 + 1) * 100 + t0 + 1] = a11;   G[(t0 + 1) * 100 + s0 + 1] = a11;
    }
  } else if (wid < 1300) {
    const int t0 = (wid - 1275) * 4;
    const float* r0 = Ht + t0 * HH;
    const float* r1 = r0 + HH;
    const float* r2 = r1 + HH;
    const float* r3 = r2 + HH;
    float a0 = 0.f, a1 = 0.f, a2 = 0.f, a3 = 0.f;
#pragma unroll 4
    for (int i = 0; i < 32; i++) {
      const int k = (lane + i * 64) * 4;
      const float4 wv = *(const float4*)(w0 + k);
      const float4 x0 = *(const float4*)(r0 + k);
      const float4 x1 = *(const float4*)(r1 + k);
      const float4 x2 = *(const float4*)(r2 + k);
      const float4 x3 = *(const float4*)(r3 + k);
      a0 += x0.x * wv.x + x0.y * wv.y + x0.z * wv.z + x0.w * wv.w;
      a1 += x1.x * wv.x + x1.y * wv.y + x1.z * wv.z + x1.w * wv.w;
      a2 += x2.x * wv.x + x2.y * wv.y + x2.z * wv.z + x2.w * wv.w;
      a3 += x3.x * wv.x + x3.y * wv.y + x3.z * wv.z + x3.w * wv.w;
    }
    a0 = wave_sum64(a0);
    a1 = wave_sum64(a1);
    a2 = wave_sum64(a2);
    a3 = wave_sum64(a3);
    if (lane == 0) {
      y0[t0] = a0;
      y0[t0 + 1] = a1;
      y0[t0 + 2] = a2;
      y0[t0 + 3] = a3;
    }
  }
}

// ---------------- K3: sequential scalar solve for err_t (1 wave)
__global__ __launch_bounds__(64) void k3_solve(const float* __restrict__ G,
                                               const float* __restrict__ y0,
                                               const float* __restrict__ ytraj,
                                               float* __restrict__ errT) {
  __shared__ float Gs[100 * 101];  // stride 101 -> conflict-free column reads
  __shared__ float y0s[100];
  __shared__ float tgt[100];
  const int l = threadIdx.x;
  for (int idx = l; idx < 10000; idx += 64) {
    Gs[(idx / 100) * 101 + (idx % 100)] = G[idx];
  }
  if (l < 50) {
    y0s[l] = y0[l];       y0s[l + 50] = y0[l + 50];
    tgt[l] = ytraj[l];    tgt[l + 50] = ytraj[l + 50];
  }
  __syncthreads();
  float e_lo = 0.f, e_hi = 0.f;  // lane l holds err_l and err_{64+l}
  for (int t = 0; t < TT; t++) {
    float contrib = 0.f;
    if (l < t) contrib += e_lo * Gs[l * 101 + t];
    if (l + 64 < t) contrib += e_hi * Gs[(l + 64) * 101 + t];
    contrib = wave_sum64(contrib);
    const float err = tgt[t] - (y0s[t] + ILR * contrib);  // uniform across wave
    if (t < 64) {
      if (l == t) e_lo = err;
    } else {
      if (l == t - 64) e_hi = err;
    }
    if (l == 0) errT[t] = err;
  }
}

// ---------------- K4: per-column forward scan (c_t, w_f) + backward suffix-product
__global__ __launch_bounds__(256) void k4_colscan(const float* __restrict__ Ht,
                                                  const float* __restrict__ errT,
                                                  const float* __restrict__ w0,
                                                  float* __restrict__ Ct,
                                                  float* __restrict__ wf) {
  __shared__ float es[100];
  const int tid = threadIdx.x;
  if (tid < 100) es[tid] = errT[tid];
  __syncthreads();
  const int j = blockIdx.x * 256 + tid;
  float w = w0[j];
#pragma unroll 4
  for (int t = 0; t < TT; t++) {
    const float h = Ht[t * HH + j];
    const float e = es[t];
    const float d = 1.f - h * h;
    w += ILR * e * h;                      // w_new (online update happens first)
    Ct[t * HH + j] = ILR * d * (e - h * w);  // c_t
  }
  wf[j] = w;
  float prod = 1.f;  // suffix product of a_s = 1 - lr*h^2 over s>t
#pragma unroll 4
  for (int t = TT - 1; t >= 0; t--) {
    Ct[t * HH + j] *= prod;
    const float h = Ht[t * HH + j];
    prod *= (1.f - ILR * h * h);
  }
}

// ---------------- K5: e_i = Hrand[i]·w_f - y_rand[i]  (one block per i)
__global__ __launch_bounds__(256) void k5_pred(const float* __restrict__ Hr,
                                               const float* __restrict__ wf,
                                               const float* __restrict__ yr,
                                               float* __restrict__ e_r) {
  const int i = blockIdx.x;
  const int tid = threadIdx.x;
  const float* row = Hr + i * HH;
  float p = 0.f;
#pragma unroll
  for (int c = tid * 4; c < HH; c += 1024) {
    const float4 h4 = *(const float4*)(row + c);
    const float4 w4 = *(const float4*)(wf + c);
    p += h4.x * w4.x + h4.y * w4.y + h4.z * w4.z + h4.w * w4.w;
  }
  p = wave_sum64(p);
  __shared__ float ps[4];
  if ((tid & 63) == 0) ps[tid >> 6] = p;
  __syncthreads();
  if (tid == 0) {
    const float y = ps[0] + ps[1] + ps[2] + ps[3];
    e_r[i] = y - yr[i];
  }
}

// ---------------- K6: v_j, M rows (v*Ct in place; U), gb = colsum(M), loss
__global__ __launch_bounds__(256) void k6_mbuild(const float* __restrict__ Hr,
                                                 const float* __restrict__ e_r,
                                                 const float* __restrict__ wf,
                                                 float* __restrict__ Ct,
                                                 float* __restrict__ U,
                                                 float* __restrict__ gb_out,
                                                 float* __restrict__ loss_out) {
  __shared__ float es[100];
  const int tid = threadIdx.x;
  if (tid < 100) es[tid] = e_r[tid];
  __syncthreads();
  if (blockIdx.x == 0 && tid < 64) {  // wave 0 of block 0: loss
    float s = es[tid] * es[tid];
    if (tid < 36) {
      const float q = es[tid + 64];
      s += q * q;
    }
    s = wave_sum64(s);
    if (tid == 0) loss_out[0] = s / (float)NN;
  }
  const int j = blockIdx.x * 256 + tid;
  const float wfj = wf[j];
  float v = 0.f;
#pragma unroll 4
  for (int i = 0; i < NN; i++) v += es[i] * Hr[i * HH + j];
  float gb = 0.f;
#pragma unroll 4
  for (int t = 0; t < TT; t++) {
    const float m = v * Ct[t * HH + j];
    Ct[t * HH + j] = m;
    gb += m;
  }
#pragma unroll 4
  for (int i = 0; i < NN; i++) {
    const float h = Hr[i * HH + j];
    const float m = es[i] * wfj * (1.f - h * h);
    U[i * HH + j] = m;
    gb += m;
  }
  gb_out[j] = gb;
}

// ---------------- K7: gW[m][j] = sum_k Xall[k][m] * Mmat[k][j]   (K=200)
__global__ __launch_bounds__(256) void k7_gw(const float* __restrict__ xt,
                                             const float* __restrict__ xr,
                                             const float* __restrict__ Mmat,
                                             float* __restrict__ gW) {
  __shared__ float As[16 * 64];  // [k][m]
  __shared__ float Bs[16 * 64];  // [k][j]
  const int tid = threadIdx.x;
  const int m0 = blockIdx.x * 64;
  const int col0 = blockIdx.y * 64;
  const int tx = tid & 15, ty = tid >> 4;
  const int lk = tid >> 4;         // 0..15
  const int lm4 = (tid & 15) * 4;  // 0..60
  float acc[4][4];
#pragma unroll
  for (int i = 0; i < 4; i++)
#pragma unroll
    for (int j = 0; j < 4; j++) acc[i][j] = 0.f;

  for (int k0 = 0; k0 < 208; k0 += 16) {
    const int gk = k0 + lk;
    float4 av, bv;
    if (gk < 200) {
      const float* asrc = (gk < TT) ? (xt + gk * DD) : (xr + (gk - TT) * DD);
      av = *(const float4*)(asrc + m0 + lm4);
      bv = *(const float4*)(Mmat + gk * HH + col0 + lm4);
    } else {
      av = make_float4(0.f, 0.f, 0.f, 0.f);
      bv = av;
    }
    __syncthreads();
    *(float4*)&As[lk * 64 + lm4] = av;
    *(float4*)&Bs[lk * 64 + lm4] = bv;
    __syncthreads();
#pragma unroll
    for (int k = 0; k < 16; k++) {
      const float4 a4 = *(const float4*)&As[k * 64 + ty * 4];
      const float4 b4 = *(const float4*)&Bs[k * 64 + tx * 4];
      const float a_[4] = {a4.x, a4.y, a4.z, a4.w};
      const float b_[4] = {b4.x, b4.y, b4.z, b4.w};
#pragma unroll
      for (int i = 0; i < 4; i++)
#pragma unroll
        for (int j = 0; j < 4; j++) acc[i][j] = fmaf(a_[i], b_[j], acc[i][j]);
    }
  }
  // gW base is d_out+1 (4B-aligned only) -> scalar stores
#pragma unroll
  for (int i = 0; i < 4; i++) {
    float* dst = gW + (m0 + ty * 4 + i) * HH + col0 + tx * 4;
    dst[0] = acc[i][0];
    dst[1] = acc[i][1];
    dst[2] = acc[i][2];
    dst[3] = acc[i][3];
  }
}

extern "C" void kernel_launch(void* const* d_in, const int* in_sizes, int n_in,
                              void* d_out, int out_size, void* d_ws, size_t ws_size,
                              hipStream_t stream) {
  (void)in_sizes; (void)n_in; (void)out_size; (void)ws_size;
  const float* xt = (const float*)d_in[0];   // [100,1024]
  const float* yt = (const float*)d_in[1];   // [100]
  const float* xr = (const float*)d_in[2];   // [100,1024]
  const float* yr = (const float*)d_in[3];   // [100]
  const float* W = (const float*)d_in[4];    // [1024,8192]
  const float* bias = (const float*)d_in[5]; // [8192]
  const float* w0 = (const float*)d_in[6];   // [8192]
  float* out = (float*)d_out;  // [0]=loss, [1..1+D*H)=gW, then gb[H]
  float* ws = (float*)d_ws;

  float* Hall = ws;              // 200*8192 (rows 0..99 Htraj, 100..199 Hrand)
  float* Ht = Hall;
  float* Hr = Hall + TT * HH;
  float* Ct = Hall + 200 * HH;   // 100*8192 -> becomes M rows 0..99
  float* U = Ct + TT * HH;       // 100*8192 -> M rows 100..199 (contiguous!)
  float* G = U + NN * HH;        // 100*100
  float* y0v = G + TT * TT;      // 100
  float* errT = y0v + TT;        // 100
  float* e_r = errT + TT;        // 100
  float* wf = e_r + NN;          // 8192

  k1_hidden<<<dim3(4, 128), 256, 0, stream>>>(xt, xr, W, bias, Hall);
  k2_gram<<<325, 256, 0, stream>>>(Ht, w0, G, y0v);
  k3_solve<<<1, 64, 0, stream>>>(G, y0v, yt, errT);
  k4_colscan<<<HH / 256, 256, 0, stream>>>(Ht, errT, w0, Ct, wf);
  k5_pred<<<NN, 256, 0, stream>>>(Hr, wf, yr, e_r);
  k6_mbuild<<<HH / 256, 256, 0, stream>>>(Hr, e_r, wf, Ct, U, out + 1 + DD * HH, out);
  k7_gw<<<dim3(DD / 64, HH / 64), 256, 0, stream>>>(xt, xr, Ct, out + 1);
}